// Round 4
// baseline (893.838 us; speedup 1.0000x reference)
//
#include <hip/hip_runtime.h>

#define NN 100000
#define NE 1600000
#define ND 64
#define HD 128
#define NBUK 512       // dst buckets (one block each)
#define NPB 196        // nodes per bucket (512*196 >= NN)
#define NB 256         // bucketing blocks
#define CH 6250        // edges per bucketing block (NE/NB)
#define ASTRIDE 72     // padded LDS aggr row stride (floats)

typedef float f32x4 __attribute__((ext_vector_type(4)));
typedef short s16x8 __attribute__((ext_vector_type(8)));

// round-to-nearest-even fp32 -> bf16 (raw short)
static __device__ __forceinline__ short f2bf(float f) {
    union { float f; unsigned u; } v; v.f = f;
    unsigned r = (v.u + 0x7fffu + ((v.u >> 16) & 1u)) >> 16;
    return (short)r;
}

// swizzled LDS index, 128-col tiles (16B chunk ^ row) -> conflict-free b128
#define LSW(n, k)   (((n) << 7) + ((((k) >> 3) ^ ((n) & 15)) << 3) + ((k) & 7))
// swizzled LDS index, 64-col tiles
#define LSW64(n, k) (((n) << 6) + ((((k) >> 3) ^ ((n) & 7)) << 3) + ((k) & 7))

// ---------------------------------------------------------------------------
// conv_bf16: x fp32 -> xb bf16
// ---------------------------------------------------------------------------
__global__ __launch_bounds__(256) void conv_bf16(const float* __restrict__ x,
                                                 short* __restrict__ xb) {
    const int NG = NN * ND / 8;
    for (int g = blockIdx.x * 256 + threadIdx.x; g < NG; g += gridDim.x * 256) {
        const float4 a = ((const float4*)x)[g * 2];
        const float4 b = ((const float4*)x)[g * 2 + 1];
        s16x8 o;
        o[0] = f2bf(a.x); o[1] = f2bf(a.y); o[2] = f2bf(a.z); o[3] = f2bf(a.w);
        o[4] = f2bf(b.x); o[5] = f2bf(b.y); o[6] = f2bf(b.z); o[7] = f2bf(b.w);
        ((s16x8*)xb)[g] = o;
    }
}

// ---------------------------------------------------------------------------
// counting sort by dst bucket (dst / NPB): hist -> scan -> scatter
// gHist/gBase layout: [bucket][block] flat = bin*NB + blk (bucket-major)
// ---------------------------------------------------------------------------
__global__ __launch_bounds__(1024) void hist512(const int* __restrict__ ei,
                                                int* __restrict__ gHist) {
    __shared__ int h[NBUK];
    const int tid = threadIdx.x;
    if (tid < NBUK) h[tid] = 0;
    __syncthreads();
    const int base = blockIdx.x * CH;
    for (int i = tid; i < CH; i += 1024)
        atomicAdd(&h[(unsigned)ei[NE + base + i] / NPB], 1);
    __syncthreads();
    if (tid < NBUK) gHist[tid * NB + blockIdx.x] = h[tid];
}

__global__ __launch_bounds__(1024) void scan131k(const int* __restrict__ gHist,
                                                 int* __restrict__ gBase) {
    // 131072 entries, 1024 threads x 128 serial + Hillis-Steele block scan
    __shared__ int A[1024], B[1024];
    const int t = threadIdx.x;
    int s = 0;
    for (int i = 0; i < 128; ++i) s += gHist[t * 128 + i];
    A[t] = s;
    __syncthreads();
    int* src = A; int* dst = B;
    for (int off = 1; off < 1024; off <<= 1) {
        int val = src[t];
        if (t >= off) val += src[t - off];
        dst[t] = val;
        __syncthreads();
        int* tmp = src; src = dst; dst = tmp;
    }
    int run = t ? src[t - 1] : 0;   // exclusive prefix of this thread's chunk
    for (int i = 0; i < 128; ++i) {
        gBase[t * 128 + i] = run;
        run += gHist[t * 128 + i];
    }
}

__global__ __launch_bounds__(1024) void scatter512(
    const int* __restrict__ ei, const float* __restrict__ ea,
    const int* __restrict__ gBase, int2* __restrict__ records) {
    __shared__ int cur[NBUK];
    const int tid = threadIdx.x;
    if (tid < NBUK) cur[tid] = gBase[tid * NB + blockIdx.x];
    __syncthreads();
    const int base = blockIdx.x * CH;
    for (int i = tid; i < CH; i += 1024) {
        const int e = base + i;
        const int s = ei[e];
        const unsigned d = (unsigned)ei[NE + e];
        const float av = ea[e];
        const unsigned bin = d / NPB;
        const int dl = (int)(d - bin * NPB);
        const int pos = atomicAdd(&cur[bin], 1);
        records[pos] = make_int2((s << 8) | dl, __float_as_int(av));
    }
}

// ---------------------------------------------------------------------------
// mpnn_fused: one block per dst bucket.
// Phase 1: per-edge MLP (MFMA) -> LDS fp32 aggr tile (LDS atomics).
// Phase 2: GRUCell (MFMA) for the bucket's nodes -> out.
// LDS: w1 32K + w2 16K + vbuf 32K + aggr 56.4K = 138368 B -> 1 block/CU.
// ---------------------------------------------------------------------------
__global__ __launch_bounds__(512) void mpnn_fused(
    const short* __restrict__ xb, const int2* __restrict__ records,
    const int* __restrict__ gBase, const float* __restrict__ x,
    const float* __restrict__ W1, const float* __restrict__ b1,
    const float* __restrict__ W2, const float* __restrict__ b2,
    const float* __restrict__ Wih, const float* __restrict__ bih,
    const float* __restrict__ Whh, const float* __restrict__ bhh,
    float* __restrict__ out)
{
    __shared__ short w1lds[128 * 128];        // 32768 B ; reused: wi (24576 B)
    __shared__ short w2lds[64 * 128];         // 16384 B
    __shared__ short vbuf[8 * 16 * 128];      // 32768 B ; reused: wh (24576 B)
    __shared__ float ldsAggr[NPB * ASTRIDE];  // 56448 B

    const int tid = threadIdx.x;

    // stage MLP weights + zero aggr tile
    for (int i = tid; i < 128 * 128; i += 512) {
        int n = i >> 7, k = i & 127;
        w1lds[LSW(n, k)] = f2bf(W1[n * 129 + k]);
    }
    for (int i = tid; i < 64 * 128; i += 512) {
        int n = i >> 7, k = i & 127;
        w2lds[LSW(n, k)] = f2bf(W2[n * 128 + k]);
    }
    for (int i = tid; i < NPB * ASTRIDE; i += 512) ldsAggr[i] = 0.f;
    __syncthreads();

    const int lane = tid & 63;
    const int w    = tid >> 6;
    const int nlo  = lane & 15;
    const int q    = lane >> 4;

    float w1l[8], b1v[8], b2v[4];
    #pragma unroll
    for (int t = 0; t < 8; ++t) {
        w1l[t] = W1[(nlo + 16 * t) * 129 + 128];
        b1v[t] = b1[nlo + 16 * t];
    }
    #pragma unroll
    for (int t = 0; t < 4; ++t) b2v[t] = b2[nlo + 16 * t];

    short* myv = vbuf + w * (16 * 128);

    const int bucket    = blockIdx.x;
    const int start     = gBase[bucket * NB];
    const int end       = (bucket < NBUK - 1) ? gBase[(bucket + 1) * NB] : NE;
    const int nodeStart = bucket * NPB;
    const int total     = min(nodeStart + NPB, NN) - nodeStart;  // may be <=0

    // ---------------- Phase 1: edges ----------------
    for (int p = start + w * 16; p < end; p += 8 * 16) {
        const int idx  = min(p + nlo, end - 1);
        const int2 rec = records[idx];
        const int sv   = rec.x >> 8;
        const int dl   = rec.x & 255;
        const float eav = __int_as_float(rec.y);

        // GEMM1: h = [x_src; x_dst] @ W1^T + b1
        f32x4 acc[8];
        #pragma unroll
        for (int t = 0; t < 8; ++t) { acc[t][0] = b1v[t]; acc[t][1] = b1v[t]; acc[t][2] = b1v[t]; acc[t][3] = b1v[t]; }

        #pragma unroll
        for (int kk = 0; kk < 4; ++kk) {
            const int row = (kk < 2) ? sv : (nodeStart + dl);
            const s16x8 af = *(const s16x8*)(xb + row * ND + ((kk & 1) << 5) + (q << 3));
            const int chunk = ((kk * 4 + q) ^ nlo) << 3;
            #pragma unroll
            for (int t = 0; t < 8; ++t) {
                const s16x8 bf = *(const s16x8*)(w1lds + ((nlo + 16 * t) << 7) + chunk);
                acc[t] = __builtin_amdgcn_mfma_f32_16x16x32_bf16(af, bf, acc[t], 0, 0, 0);
            }
        }

        // epilogue1: + ea * W1[:,128], relu, bf16, transpose via per-wave LDS
        float ear[4];
        #pragma unroll
        for (int r = 0; r < 4; ++r) ear[r] = __shfl(eav, q * 4 + r, 64);
        #pragma unroll
        for (int t = 0; t < 8; ++t) {
            #pragma unroll
            for (int r = 0; r < 4; ++r) {
                const float hv = fmaxf(acc[t][r] + ear[r] * w1l[t], 0.f);
                const int m = q * 4 + r;
                const int k = nlo + 16 * t;
                myv[LSW(m, k)] = f2bf(hv);
            }
        }

        // GEMM2: m = relu(h) @ W2^T + b2
        f32x4 acc2[4];
        #pragma unroll
        for (int t = 0; t < 4; ++t) { acc2[t][0] = b2v[t]; acc2[t][1] = b2v[t]; acc2[t][2] = b2v[t]; acc2[t][3] = b2v[t]; }

        #pragma unroll
        for (int kk = 0; kk < 4; ++kk) {
            const int chunk = ((kk * 4 + q) ^ nlo) << 3;
            const s16x8 af = *(const s16x8*)(myv + (nlo << 7) + chunk);
            #pragma unroll
            for (int t = 0; t < 4; ++t) {
                const s16x8 bf = *(const s16x8*)(w2lds + ((nlo + 16 * t) << 7) + chunk);
                acc2[t] = __builtin_amdgcn_mfma_f32_16x16x32_bf16(af, bf, acc2[t], 0, 0, 0);
            }
        }

        // scatter into LDS aggr tile (fp32 LDS atomics, ~2-way banked)
        #pragma unroll
        for (int r = 0; r < 4; ++r) {
            const int m   = q * 4 + r;
            const int dlm = __shfl(dl, m, 64);
            if (p + m < end) {
                float* ap = ldsAggr + dlm * ASTRIDE + nlo;
                atomicAdd(ap +  0, acc2[0][r]);
                atomicAdd(ap + 16, acc2[1][r]);
                atomicAdd(ap + 32, acc2[2][r]);
                atomicAdd(ap + 48, acc2[3][r]);
            }
        }
    }

    __syncthreads();   // all edges of this bucket aggregated

    // ---------------- Phase 2: GRU ----------------
    short* wi = w1lds;   // 192*64 bf16 = 24576 B
    short* wh = vbuf;
    for (int i = tid; i < 192 * 64; i += 512) {
        int n = i >> 6, k = i & 63;
        wi[LSW64(n, k)] = f2bf(Wih[i]);
        wh[LSW64(n, k)] = f2bf(Whh[i]);
    }
    __syncthreads();

    if (total <= 0) return;

    float bi[12], bh[12];
    #pragma unroll
    for (int t = 0; t < 12; ++t) { bi[t] = bih[16 * t + nlo]; bh[t] = bhh[16 * t + nlo]; }

    for (int lt = w; lt * 16 < total; lt += 8) {
        const int n0loc = lt * 16;
        f32x4 ai[12], ah[12];
        #pragma unroll
        for (int t = 0; t < 12; ++t) {
            ai[t][0] = bi[t]; ai[t][1] = bi[t]; ai[t][2] = bi[t]; ai[t][3] = bi[t];
            ah[t][0] = bh[t]; ah[t][1] = bh[t]; ah[t][2] = bh[t]; ah[t][3] = bh[t];
        }

        const int cl = min(n0loc + nlo, total - 1);   // clamped local node (A row)
        #pragma unroll
        for (int kk = 0; kk < 2; ++kk) {
            const float* ap = ldsAggr + cl * ASTRIDE + kk * 32 + q * 8;
            const float* xp = x + (size_t)(nodeStart + cl) * ND + kk * 32 + q * 8;
            const float4 x0 = *(const float4*)(xp);
            const float4 x1 = *(const float4*)(xp + 4);
            s16x8 fA, fX;
            #pragma unroll
            for (int j = 0; j < 8; ++j) fA[j] = f2bf(ap[j]);
            fX[0] = f2bf(x0.x); fX[1] = f2bf(x0.y); fX[2] = f2bf(x0.z); fX[3] = f2bf(x0.w);
            fX[4] = f2bf(x1.x); fX[5] = f2bf(x1.y); fX[6] = f2bf(x1.z); fX[7] = f2bf(x1.w);
            const int chunk = kk * 4 + q;
            #pragma unroll
            for (int t = 0; t < 12; ++t) {
                const int rb = 16 * t + nlo;
                const int boff = (rb << 6) + ((chunk ^ (rb & 7)) << 3);
                const s16x8 bI = *(const s16x8*)(wi + boff);
                const s16x8 bH = *(const s16x8*)(wh + boff);
                ai[t] = __builtin_amdgcn_mfma_f32_16x16x32_bf16(fA, bI, ai[t], 0, 0, 0);
                ah[t] = __builtin_amdgcn_mfma_f32_16x16x32_bf16(fX, bH, ah[t], 0, 0, 0);
            }
        }

        #pragma unroll
        for (int t = 0; t < 4; ++t) {
            #pragma unroll
            for (int r = 0; r < 4; ++r) {
                const int nodeLoc = n0loc + q * 4 + r;
                if (nodeLoc < total) {
                    const int node = nodeStart + nodeLoc;
                    const int c    = nlo + 16 * t;
                    const float rr = 1.f / (1.f + __expf(-(ai[t][r] + ah[t][r])));
                    const float zz = 1.f / (1.f + __expf(-(ai[t + 4][r] + ah[t + 4][r])));
                    const float nv = ai[t + 8][r] + rr * ah[t + 8][r];
                    const float nn = 2.f / (1.f + __expf(-2.f * nv)) - 1.f;   // tanh
                    const float xv = x[(size_t)node * ND + c];
                    out[(size_t)node * ND + c] = (1.f - zz) * nn + zz * xv;
                }
            }
        }
    }
}

extern "C" void kernel_launch(void* const* d_in, const int* in_sizes, int n_in,
                              void* d_out, int out_size, void* d_ws, size_t ws_size,
                              hipStream_t stream) {
    const float* x   = (const float*)d_in[0];
    const int*   ei  = (const int*)d_in[1];
    const float* ea  = (const float*)d_in[2];
    const float* W1  = (const float*)d_in[3];
    const float* b1  = (const float*)d_in[4];
    const float* W2  = (const float*)d_in[5];
    const float* b2  = (const float*)d_in[6];
    const float* Wih = (const float*)d_in[7];
    const float* bih = (const float*)d_in[8];
    const float* Whh = (const float*)d_in[9];
    const float* bhh = (const float*)d_in[10];
    float* out = (float*)d_out;

    // workspace layout (~26.6 MB)
    char* ws = (char*)d_ws;
    short* xb      = (short*)(ws);                 // 12,800,000 B
    int2*  records = (int2*) (ws + 12800000);      // 12,800,000 B
    int*   gHist   = (int*)  (ws + 25600000);      //    524,288 B
    int*   gBase   = (int*)  (ws + 26124288);      //    524,288 B

    hipLaunchKernelGGL(conv_bf16, dim3(512), dim3(256), 0, stream, x, xb);
    hipLaunchKernelGGL(hist512, dim3(NB), dim3(1024), 0, stream, ei, gHist);
    hipLaunchKernelGGL(scan131k, dim3(1), dim3(1024), 0, stream, gHist, gBase);
    hipLaunchKernelGGL(scatter512, dim3(NB), dim3(1024), 0, stream,
                       ei, ea, gBase, records);
    hipLaunchKernelGGL(mpnn_fused, dim3(NBUK), dim3(512), 0, stream,
                       xb, records, gBase, x, W1, b1, W2, b2,
                       Wih, bih, Whh, bhh, out);
}